// Round 1
// baseline (755.311 us; speedup 1.0000x reference)
//
#include <hip/hip_runtime.h>
#include <hip/hip_bf16.h>

// GraphSAGE 2-layer forward on MI355X.
// Pipeline: deg -> scan -> CSR fill -> agg(x) -> gemm1(relu) -> agg(h) -> gemm2
// agg-first formulation: h = relu([x | Ax] @ [W1s; W1n] + b1), out = [h | Ah] @ [W2s; W2n] + b2

#define D_FEAT 128

// ---------------- degree ----------------
__global__ __launch_bounds__(256) void deg_kernel(const int* __restrict__ dst, int* __restrict__ deg, int e) {
    int i = blockIdx.x * 256 + threadIdx.x;
    if (i < e) atomicAdd(&deg[dst[i]], 1);
}

// ---------------- 3-kernel exclusive scan (n <= 128*1024) ----------------
__global__ __launch_bounds__(1024) void scan1(const int* __restrict__ deg, int* __restrict__ incl,
                                              int* __restrict__ blk, int n) {
    __shared__ int sm[1024];
    int i = blockIdx.x * 1024 + threadIdx.x;
    int v = (i < n) ? deg[i] : 0;
    sm[threadIdx.x] = v;
    __syncthreads();
    for (int off = 1; off < 1024; off <<= 1) {
        int t = (threadIdx.x >= off) ? sm[threadIdx.x - off] : 0;
        __syncthreads();
        sm[threadIdx.x] += t;
        __syncthreads();
    }
    if (i < n) incl[i] = sm[threadIdx.x];
    if (threadIdx.x == 1023) blk[blockIdx.x] = sm[1023];
}

__global__ __launch_bounds__(128) void scan2(int* __restrict__ blk, int nb) {
    __shared__ int sm[128];
    int tid = threadIdx.x;
    int v = (tid < nb) ? blk[tid] : 0;
    sm[tid] = v;
    __syncthreads();
    for (int off = 1; off < 128; off <<= 1) {
        int t = (tid >= off) ? sm[tid - off] : 0;
        __syncthreads();
        sm[tid] += t;
        __syncthreads();
    }
    if (tid < nb) blk[tid] = (tid == 0) ? 0 : sm[tid - 1];  // exclusive block offsets
}

__global__ __launch_bounds__(1024) void scan3(const int* __restrict__ incl, const int* __restrict__ blk,
                                              const int* __restrict__ deg, int* __restrict__ row_start,
                                              float* __restrict__ inv_deg, int n) {
    int i = blockIdx.x * 1024 + threadIdx.x;
    if (i < n) {
        row_start[i + 1] = incl[i] + blk[blockIdx.x];
        if (i == 0) row_start[0] = 0;
        int d = deg[i];
        inv_deg[i] = (d > 0) ? (1.0f / (float)d) : 0.0f;
    }
}

// ---------------- CSR fill (counting sort by dst) ----------------
__global__ __launch_bounds__(256) void csr_fill(const int* __restrict__ src, const int* __restrict__ dst,
                                                const int* __restrict__ row_start, int* __restrict__ cursor,
                                                int* __restrict__ csr_src, int e) {
    int i = blockIdx.x * 256 + threadIdx.x;
    if (i < e) {
        int d = dst[i];
        int pos = row_start[d] + atomicAdd(&cursor[d], 1);
        csr_src[pos] = src[i];
    }
}

// ---------------- aggregation: wave-per-node mean of in-neighbors ----------------
__global__ __launch_bounds__(256) void aggregate(const float* __restrict__ feat, const int* __restrict__ row_start,
                                                 const int* __restrict__ csr_src, const float* __restrict__ inv_deg,
                                                 float* __restrict__ out, int n) {
    int wid = (blockIdx.x * 256 + threadIdx.x) >> 6;  // one wave per node
    int lane = threadIdx.x & 63;
    if (wid >= n) return;
    int beg = row_start[wid];
    int end = row_start[wid + 1];
    const float2* f2 = (const float2*)feat;
    float ax = 0.f, ay = 0.f;
    for (int ei = beg; ei < end; ++ei) {
        int s = csr_src[ei];
        float2 v = f2[(size_t)s * 64 + lane];
        ax += v.x;
        ay += v.y;
    }
    float w = inv_deg[wid];
    float2 o;
    o.x = ax * w;
    o.y = ay * w;
    ((float2*)out)[(size_t)wid * 64 + lane] = o;
}

// ---------------- concatenated GEMM:  Y = [A1|A2] @ [W1;W2] + b  (optional relu) ----------------
// A1,A2: [n][128] row-major; W1,W2: [128][BN] row-major; Y: [n][BN]
template <int BN, bool RELU>
__global__ __launch_bounds__(256) void gemm_cat(const float* __restrict__ A1, const float* __restrict__ A2,
                                                const float* __restrict__ W1, const float* __restrict__ W2,
                                                const float* __restrict__ bias, float* __restrict__ Y, int n) {
    constexpr int TX = BN / 8;     // threads along N
    constexpr int TY = 256 / TX;   // threads along M
    constexpr int BM = TY * 8;     // rows per block
    constexpr int KT = 32;

    __shared__ float As[KT][BM + 4];  // transposed A tile: As[k][m]
    __shared__ float Ws[KT][BN];

    int tid = threadIdx.x;
    int tx = tid % TX;
    int ty = tid / TX;
    int m0 = blockIdx.x * BM;

    float acc[8][8];
#pragma unroll
    for (int i = 0; i < 8; ++i)
#pragma unroll
        for (int j = 0; j < 8; ++j) acc[i][j] = 0.f;

    for (int kt = 0; kt < 8; ++kt) {
        const float* A = (kt < 4) ? A1 : A2;
        const float* W = (kt < 4) ? W1 : W2;
        int k0 = (kt & 3) * KT;

        // stage A transposed: BM rows x 32 k, as float4 loads
        constexpr int F = BM * 8;  // float4 count
        for (int f = tid; f < F; f += 256) {
            int row = f >> 3, c = f & 7;
            int grow = m0 + row;
            float4 v = make_float4(0.f, 0.f, 0.f, 0.f);
            if (grow < n) v = *(const float4*)&A[(size_t)grow * 128 + k0 + 4 * c];
            As[4 * c + 0][row] = v.x;
            As[4 * c + 1][row] = v.y;
            As[4 * c + 2][row] = v.z;
            As[4 * c + 3][row] = v.w;
        }
        // stage W rows
        constexpr int FW = KT * BN / 4;
        for (int f = tid; f < FW; f += 256) {
            int k = f / (BN / 4), c = f % (BN / 4);
            *(float4*)&Ws[k][4 * c] = *(const float4*)&W[(size_t)(k0 + k) * BN + 4 * c];
        }
        __syncthreads();

#pragma unroll 8
        for (int k = 0; k < KT; ++k) {
            float4 a0 = *(const float4*)&As[k][ty * 8];
            float4 a1 = *(const float4*)&As[k][ty * 8 + 4];
            float4 b0 = *(const float4*)&Ws[k][tx * 8];
            float4 b1 = *(const float4*)&Ws[k][tx * 8 + 4];
            float a[8] = {a0.x, a0.y, a0.z, a0.w, a1.x, a1.y, a1.z, a1.w};
            float b[8] = {b0.x, b0.y, b0.z, b0.w, b1.x, b1.y, b1.z, b1.w};
#pragma unroll
            for (int i = 0; i < 8; ++i)
#pragma unroll
                for (int j = 0; j < 8; ++j) acc[i][j] += a[i] * b[j];
        }
        __syncthreads();
    }

    // epilogue: bias (+relu), vectorized store
    float bv[8];
    *(float4*)&bv[0] = *(const float4*)&bias[tx * 8];
    *(float4*)&bv[4] = *(const float4*)&bias[tx * 8 + 4];
#pragma unroll
    for (int i = 0; i < 8; ++i) {
        int grow = m0 + ty * 8 + i;
        if (grow >= n) continue;
        float o[8];
#pragma unroll
        for (int j = 0; j < 8; ++j) {
            float v = acc[i][j] + bv[j];
            if (RELU) v = fmaxf(v, 0.f);
            o[j] = v;
        }
        *(float4*)&Y[(size_t)grow * BN + tx * 8] = *(const float4*)&o[0];
        *(float4*)&Y[(size_t)grow * BN + tx * 8 + 4] = *(const float4*)&o[4];
    }
}

extern "C" void kernel_launch(void* const* d_in, const int* in_sizes, int n_in,
                              void* d_out, int out_size, void* d_ws, size_t ws_size,
                              hipStream_t stream) {
    const float* x   = (const float*)d_in[0];
    const int*   src = (const int*)d_in[1];
    const int*   dst = (const int*)d_in[2];
    const float* W1s = (const float*)d_in[3];
    const float* W1n = (const float*)d_in[4];
    const float* b1  = (const float*)d_in[5];
    const float* W2s = (const float*)d_in[6];
    const float* W2n = (const float*)d_in[7];
    const float* b2  = (const float*)d_in[8];
    float* out = (float*)d_out;

    const int n = in_sizes[0] / D_FEAT;  // 100000
    const int e = in_sizes[1];           // 1600000

    // ---- workspace carve (256B aligned slabs) ----
    char* ws = (char*)d_ws;
    auto take = [&](size_t bytes) {
        void* p = (void*)ws;
        ws += (bytes + 255) & ~(size_t)255;
        return p;
    };
    int*   deg       = (int*)take((size_t)n * 4);
    int*   cursor    = (int*)take((size_t)n * 4);
    int*   row_start = (int*)take((size_t)(n + 1) * 4);
    int*   incl      = (int*)take((size_t)n * 4);
    int*   blk       = (int*)take(128 * 4);
    int*   csr_src   = (int*)take((size_t)e * 4);
    float* inv_deg   = (float*)take((size_t)n * 4);
    float* agg       = (float*)take((size_t)n * D_FEAT * 4);
    float* h         = (float*)take((size_t)n * D_FEAT * 4);

    // zero deg + cursor (contiguous region)
    hipMemsetAsync(deg, 0, (size_t)((char*)row_start - (char*)deg), stream);

    const int nb = (n + 1023) / 1024;

    deg_kernel<<<(e + 255) / 256, 256, 0, stream>>>(dst, deg, e);
    scan1<<<nb, 1024, 0, stream>>>(deg, incl, blk, n);
    scan2<<<1, 128, 0, stream>>>(blk, nb);
    scan3<<<nb, 1024, 0, stream>>>(incl, blk, deg, row_start, inv_deg, n);
    csr_fill<<<(e + 255) / 256, 256, 0, stream>>>(src, dst, row_start, cursor, csr_src, e);

    // layer 1
    aggregate<<<(n * 64 + 255) / 256, 256, 0, stream>>>(x, row_start, csr_src, inv_deg, agg, n);
    gemm_cat<128, true><<<(n + 127) / 128, 256, 0, stream>>>(x, agg, W1s, W1n, b1, h, n);

    // layer 2
    aggregate<<<(n * 64 + 255) / 256, 256, 0, stream>>>(h, row_start, csr_src, inv_deg, agg, n);
    gemm_cat<64, false><<<(n + 255) / 256, 256, 0, stream>>>(h, agg, W2s, W2n, b2, out, n);
}

// Round 2
// 454.030 us; speedup vs baseline: 1.6636x; 1.6636x over previous
//
#include <hip/hip_runtime.h>
#include <hip/hip_bf16.h>

// GraphSAGE 2-layer forward, bf16 datapath.
// xcat/hcat: [n][256] bf16 rows = [feat(128) | agg(128)] -> one contiguous GEMM A operand.
// Weights pre-converted to Wcat[N][256] bf16 (B^T layout, K=256 = [self;neigh]).
// agg: 4 edges/iter, 16 lanes x uint4 per edge row, f32 accum, shfl_xor combine.
// GEMM: mfma_f32_16x16x32_bf16, 4 waves x 32 rows, W in LDS (XOR-swizzled, 2 K-chunks).

#define D_FEAT 128

typedef __attribute__((ext_vector_type(8))) short bf16x8;
typedef __attribute__((ext_vector_type(4))) float f32x4;

__device__ __forceinline__ ushort f2bf(float f) {
    __hip_bfloat16 h = __float2bfloat16(f);
    return *(ushort*)&h;
}
__device__ __forceinline__ uint pack2(float lo, float hi) {
    return (uint)f2bf(lo) | ((uint)f2bf(hi) << 16);
}

// ---------------- degree ----------------
__global__ __launch_bounds__(256) void deg_kernel(const int* __restrict__ dst, int* __restrict__ deg, int e) {
    int i = blockIdx.x * 256 + threadIdx.x;
    if (i < e) atomicAdd(&deg[dst[i]], 1);
}

// ---------------- 3-kernel exclusive scan ----------------
__global__ __launch_bounds__(1024) void scan1(const int* __restrict__ deg, int* __restrict__ incl,
                                              int* __restrict__ blk, int n) {
    __shared__ int sm[1024];
    int i = blockIdx.x * 1024 + threadIdx.x;
    int v = (i < n) ? deg[i] : 0;
    sm[threadIdx.x] = v;
    __syncthreads();
    for (int off = 1; off < 1024; off <<= 1) {
        int t = (threadIdx.x >= off) ? sm[threadIdx.x - off] : 0;
        __syncthreads();
        sm[threadIdx.x] += t;
        __syncthreads();
    }
    if (i < n) incl[i] = sm[threadIdx.x];
    if (threadIdx.x == 1023) blk[blockIdx.x] = sm[1023];
}

__global__ __launch_bounds__(128) void scan2(int* __restrict__ blk, int nb) {
    __shared__ int sm[128];
    int tid = threadIdx.x;
    int v = (tid < nb) ? blk[tid] : 0;
    sm[tid] = v;
    __syncthreads();
    for (int off = 1; off < 128; off <<= 1) {
        int t = (tid >= off) ? sm[tid - off] : 0;
        __syncthreads();
        sm[tid] += t;
        __syncthreads();
    }
    if (tid < nb) blk[tid] = (tid == 0) ? 0 : sm[tid - 1];
}

__global__ __launch_bounds__(1024) void scan3(const int* __restrict__ incl, const int* __restrict__ blk,
                                              const int* __restrict__ deg, int* __restrict__ row_start,
                                              float* __restrict__ inv_deg, int n) {
    int i = blockIdx.x * 1024 + threadIdx.x;
    if (i < n) {
        row_start[i + 1] = incl[i] + blk[blockIdx.x];
        if (i == 0) row_start[0] = 0;
        int d = deg[i];
        inv_deg[i] = (d > 0) ? (1.0f / (float)d) : 0.0f;
    }
}

// ---------------- CSR fill ----------------
__global__ __launch_bounds__(256) void csr_fill(const int* __restrict__ src, const int* __restrict__ dst,
                                                const int* __restrict__ row_start, int* __restrict__ cursor,
                                                int* __restrict__ csr_src, int e) {
    int i = blockIdx.x * 256 + threadIdx.x;
    if (i < e) {
        int d = dst[i];
        int pos = row_start[d] + atomicAdd(&cursor[d], 1);
        csr_src[pos] = src[i];
    }
}

// ---------------- feature convert: f32 [n][128] -> bf16 cols 0..127 of [n][256] ----------------
__global__ __launch_bounds__(256) void convert_x(const float* __restrict__ x, ushort* __restrict__ xcat, int total8) {
    int i = blockIdx.x * 256 + threadIdx.x;
    if (i >= total8) return;
    int e = i * 8;
    int row = e >> 7, col = e & 127;
    float4 v0 = *(const float4*)(x + e);
    float4 v1 = *(const float4*)(x + e + 4);
    uint4 o;
    o.x = pack2(v0.x, v0.y);
    o.y = pack2(v0.z, v0.w);
    o.z = pack2(v1.x, v1.y);
    o.w = pack2(v1.z, v1.w);
    *(uint4*)(xcat + (size_t)row * 256 + col) = o;
}

// ---------------- weight convert: W1cat[128][256], W2cat[64][256] bf16 (B^T, K-concat) ----------------
__global__ __launch_bounds__(256) void convert_w(const float* __restrict__ W1s, const float* __restrict__ W1n,
                                                 const float* __restrict__ W2s, const float* __restrict__ W2n,
                                                 ushort* __restrict__ w1cat, ushort* __restrict__ w2cat) {
    int idx = blockIdx.x * 256 + threadIdx.x;
    if (idx < 128 * 256) {
        int c = idx >> 8, k = idx & 255;
        float v = (k < 128) ? W1s[k * 128 + c] : W1n[(k - 128) * 128 + c];
        w1cat[idx] = f2bf(v);
    } else if (idx < 128 * 256 + 64 * 256) {
        int j = idx - 128 * 256;
        int c = j >> 8, k = j & 255;
        float v = (k < 128) ? W2s[k * 64 + c] : W2n[(k - 128) * 64 + c];
        w2cat[j] = f2bf(v);
    }
}

// ---------------- aggregation: wave per node, 4 edges/iter, bf16 rows of 256B ----------------
__global__ __launch_bounds__(256) void aggregate_bf16(const ushort* __restrict__ featbase,
                                                      const int* __restrict__ row_start,
                                                      const int* __restrict__ csr_src,
                                                      const float* __restrict__ inv_deg,
                                                      ushort* __restrict__ outbase, int n) {
    int wid = (blockIdx.x * 256 + threadIdx.x) >> 6;
    if (wid >= n) return;
    int lane = threadIdx.x & 63;
    int grp = lane >> 4, gl = lane & 15;

    int beg = row_start[wid];
    int end = row_start[wid + 1];

    float a[8];
#pragma unroll
    for (int j = 0; j < 8; ++j) a[j] = 0.f;

    for (int ei = beg + grp; ei < end; ei += 4) {
        int s = csr_src[ei];
        uint4 v = *(const uint4*)(featbase + (size_t)s * 256 + gl * 8);
        a[0] += __uint_as_float(v.x << 16);
        a[1] += __uint_as_float(v.x & 0xffff0000u);
        a[2] += __uint_as_float(v.y << 16);
        a[3] += __uint_as_float(v.y & 0xffff0000u);
        a[4] += __uint_as_float(v.z << 16);
        a[5] += __uint_as_float(v.z & 0xffff0000u);
        a[6] += __uint_as_float(v.w << 16);
        a[7] += __uint_as_float(v.w & 0xffff0000u);
    }
#pragma unroll
    for (int j = 0; j < 8; ++j) {
        a[j] += __shfl_xor(a[j], 16);
        a[j] += __shfl_xor(a[j], 32);
    }
    if (grp == 0) {
        float w = inv_deg[wid];
        uint4 o;
        o.x = pack2(a[0] * w, a[1] * w);
        o.y = pack2(a[2] * w, a[3] * w);
        o.z = pack2(a[4] * w, a[5] * w);
        o.w = pack2(a[6] * w, a[7] * w);
        *(uint4*)(outbase + (size_t)wid * 256 + gl * 8) = o;
    }
}

// ---------------- MFMA GEMM: Y[n][NCOL] = A[n][256] @ Wcat^T + bias ----------------
// A bf16 rows of 256; Wcat [NCOL][256] bf16 (B^T). 4 waves x 32 rows = 128 rows/block.
template <int NTILES, bool RELU, bool OUTBF16>
__global__ __launch_bounds__(256) void gemm_mfma(const ushort* __restrict__ A, const ushort* __restrict__ Wcat,
                                                 const float* __restrict__ bias, ushort* __restrict__ Yb,
                                                 float* __restrict__ Yf, int n) {
    constexpr int NCOL = NTILES * 16;
    __shared__ ushort Wlds[NCOL * 128];  // one 128-K chunk, XOR-swizzled rows of 256B

    int tid = threadIdx.x;
    int wave = tid >> 6, lane = tid & 63;
    int lrow = lane & 15, lk = lane >> 4;
    int m0 = blockIdx.x * 128 + wave * 32;

    int mA = min(m0 + lrow, n - 1);
    int mB = min(m0 + 16 + lrow, n - 1);
    const ushort* Arow0 = A + (size_t)mA * 256;
    const ushort* Arow1 = A + (size_t)mB * 256;

    f32x4 acc[2][NTILES];
#pragma unroll
    for (int mi = 0; mi < 2; ++mi)
#pragma unroll
        for (int nj = 0; nj < NTILES; ++nj) acc[mi][nj] = (f32x4)0.f;

    for (int chunk = 0; chunk < 2; ++chunk) {
        // stage W chunk: NCOL rows x 128 k
        for (int f = tid; f < NCOL * 16; f += 256) {
            int c = f >> 4;
            int kk = (f & 15) * 8;
            uint4 w = *(const uint4*)(Wcat + c * 256 + chunk * 128 + kk);
            uint baddr = ((uint)(c * 256 + kk * 2)) ^ ((uint)(c & 7) << 4);
            *(uint4*)((char*)Wlds + baddr) = w;
        }
        __syncthreads();

#pragma unroll
        for (int ks = 0; ks < 4; ++ks) {
            int kbase = chunk * 128 + ks * 32 + lk * 8;
            bf16x8 a0 = *(const bf16x8*)(Arow0 + kbase);
            bf16x8 a1 = *(const bf16x8*)(Arow1 + kbase);
#pragma unroll
            for (int nj = 0; nj < NTILES; ++nj) {
                int c = nj * 16 + lrow;
                uint baddr = ((uint)(c * 256 + (ks * 32 + lk * 8) * 2)) ^ ((uint)(c & 7) << 4);
                bf16x8 b = *(const bf16x8*)((const char*)Wlds + baddr);
                acc[0][nj] = __builtin_amdgcn_mfma_f32_16x16x32_bf16(a0, b, acc[0][nj], 0, 0, 0);
                acc[1][nj] = __builtin_amdgcn_mfma_f32_16x16x32_bf16(a1, b, acc[1][nj], 0, 0, 0);
            }
        }
        __syncthreads();
    }

    // epilogue: C/D layout col=lane&15, row=(lane>>4)*4+r  [m89]
#pragma unroll
    for (int nj = 0; nj < NTILES; ++nj) {
        int col = nj * 16 + lrow;
        float bv = bias[col];
#pragma unroll
        for (int mi = 0; mi < 2; ++mi) {
#pragma unroll
            for (int r = 0; r < 4; ++r) {
                int row = m0 + mi * 16 + lk * 4 + r;
                if (row >= n) continue;
                float v = acc[mi][nj][r] + bv;
                if (RELU) v = fmaxf(v, 0.f);
                if (OUTBF16)
                    Yb[(size_t)row * 256 + col] = f2bf(v);
                else
                    Yf[(size_t)row * 64 + col] = v;
            }
        }
    }
}

extern "C" void kernel_launch(void* const* d_in, const int* in_sizes, int n_in,
                              void* d_out, int out_size, void* d_ws, size_t ws_size,
                              hipStream_t stream) {
    const float* x   = (const float*)d_in[0];
    const int*   src = (const int*)d_in[1];
    const int*   dst = (const int*)d_in[2];
    const float* W1s = (const float*)d_in[3];
    const float* W1n = (const float*)d_in[4];
    const float* b1  = (const float*)d_in[5];
    const float* W2s = (const float*)d_in[6];
    const float* W2n = (const float*)d_in[7];
    const float* b2  = (const float*)d_in[8];
    float* out = (float*)d_out;

    const int n = in_sizes[0] / D_FEAT;  // 100000
    const int e = in_sizes[1];           // 1600000

    // ---- workspace carve ----
    char* ws = (char*)d_ws;
    auto take = [&](size_t bytes) {
        void* p = (void*)ws;
        ws += (bytes + 255) & ~(size_t)255;
        return p;
    };
    int*    deg       = (int*)take((size_t)n * 4);
    int*    cursor    = (int*)take((size_t)n * 4);
    int*    row_start = (int*)take((size_t)(n + 1) * 4);
    int*    incl      = (int*)take((size_t)n * 4);
    int*    blk       = (int*)take(128 * 4);
    int*    csr_src   = (int*)take((size_t)e * 4);
    float*  inv_deg   = (float*)take((size_t)n * 4);
    ushort* xcat      = (ushort*)take((size_t)n * 256 * 2);
    ushort* hcat      = (ushort*)take((size_t)n * 256 * 2);
    ushort* w1cat     = (ushort*)take((size_t)128 * 256 * 2);
    ushort* w2cat     = (ushort*)take((size_t)64 * 256 * 2);

    hipMemsetAsync(deg, 0, (size_t)((char*)row_start - (char*)deg), stream);

    const int nb = (n + 1023) / 1024;

    convert_w<<<(128 * 256 + 64 * 256 + 255) / 256, 256, 0, stream>>>(W1s, W1n, W2s, W2n, w1cat, w2cat);
    convert_x<<<(n * 16 + 255) / 256, 256, 0, stream>>>(x, xcat, n * 16);

    deg_kernel<<<(e + 255) / 256, 256, 0, stream>>>(dst, deg, e);
    scan1<<<nb, 1024, 0, stream>>>(deg, incl, blk, n);
    scan2<<<1, 128, 0, stream>>>(blk, nb);
    scan3<<<nb, 1024, 0, stream>>>(incl, blk, deg, row_start, inv_deg, n);
    csr_fill<<<(e + 255) / 256, 256, 0, stream>>>(src, dst, row_start, cursor, csr_src, e);

    // layer 1: agg(x) -> xcat[:,128:], then h = relu([x|agg] @ W1cat^T + b1) -> hcat[:,0:128]
    aggregate_bf16<<<n / 4, 256, 0, stream>>>(xcat, row_start, csr_src, inv_deg, xcat + 128, n);
    gemm_mfma<8, true, true><<<(n + 127) / 128, 256, 0, stream>>>(xcat, w1cat, b1, hcat, nullptr, n);

    // layer 2: agg(h) -> hcat[:,128:], then out = [h|agg] @ W2cat^T + b2
    aggregate_bf16<<<n / 4, 256, 0, stream>>>(hcat, row_start, csr_src, inv_deg, hcat + 128, n);
    gemm_mfma<4, false, false><<<(n + 127) / 128, 256, 0, stream>>>(hcat, w2cat, b2, nullptr, out, n);
}

// Round 3
// 371.661 us; speedup vs baseline: 2.0323x; 1.2216x over previous
//
#include <hip/hip_runtime.h>
#include <hip/hip_bf16.h>

// GraphSAGE 2-layer forward, bf16 datapath + cache-line-aware CSR build.
// CSR build: bucket_hist -> bucket_scan -> bin_edges (LDS multisplit, coalesced
// line flushes) -> build_bucket (per-bucket LDS count/scan/place; writes stay in
// one XCD's L2). Replaces deg/scan1-3/csr_fill (107MB write-allocate scatter).
// xcat/hcat: [n][256] bf16 rows = [feat(128) | agg(128)]; Wcat[N][256] bf16 B^T.

#define D_FEAT 128
#define MAXNB 128   // max buckets (n <= 131072), bucket = 1024 nodes
#define CAP 40      // LDS stash capacity per bucket per block-batch (mean ~21)

typedef __attribute__((ext_vector_type(8))) short bf16x8;
typedef __attribute__((ext_vector_type(4))) float f32x4;

__device__ __forceinline__ ushort f2bf(float f) {
    __hip_bfloat16 h = __float2bfloat16(f);
    return *(ushort*)&h;
}
__device__ __forceinline__ uint pack2(float lo, float hi) {
    return (uint)f2bf(lo) | ((uint)f2bf(hi) << 16);
}

// ---------------- bucket histogram: per-block LDS, one atomic/bucket/block ----------------
__global__ __launch_bounds__(256) void bucket_hist(const int* __restrict__ dst, int* __restrict__ bucket_cnt,
                                                   int e, int nb) {
    __shared__ int h[MAXNB];
    int tid = threadIdx.x;
    if (tid < MAXNB) h[tid] = 0;
    __syncthreads();
    int i0 = blockIdx.x * 2048 + tid * 8;
    if (i0 + 8 <= e) {
        int4 a = *(const int4*)(dst + i0);
        int4 b = *(const int4*)(dst + i0 + 4);
        atomicAdd(&h[a.x >> 10], 1);
        atomicAdd(&h[a.y >> 10], 1);
        atomicAdd(&h[a.z >> 10], 1);
        atomicAdd(&h[a.w >> 10], 1);
        atomicAdd(&h[b.x >> 10], 1);
        atomicAdd(&h[b.y >> 10], 1);
        atomicAdd(&h[b.z >> 10], 1);
        atomicAdd(&h[b.w >> 10], 1);
    } else {
        for (int k = 0; k < 8; ++k)
            if (i0 + k < e) atomicAdd(&h[dst[i0 + k] >> 10], 1);
    }
    __syncthreads();
    if (tid < nb && h[tid]) atomicAdd(&bucket_cnt[tid], h[tid]);
}

// ---------------- bucket scan: bases for temp regions == row_start at bucket bounds ----------------
__global__ __launch_bounds__(128) void bucket_scan(const int* __restrict__ bucket_cnt, int* __restrict__ bucket_base,
                                                   int* __restrict__ gcur, int* __restrict__ row_start,
                                                   int nb, int n, int e) {
    __shared__ int sm[128];
    int tid = threadIdx.x;
    int v = (tid < nb) ? bucket_cnt[tid] : 0;
    sm[tid] = v;
    __syncthreads();
    for (int off = 1; off < 128; off <<= 1) {
        int t = (tid >= off) ? sm[tid - off] : 0;
        __syncthreads();
        sm[tid] += t;
        __syncthreads();
    }
    if (tid < nb) {
        int excl = sm[tid] - v;
        bucket_base[tid] = excl;
        gcur[tid] = excl;
    }
    if (tid == nb) bucket_base[tid] = e;  // nb < 128
    if (tid == 0) row_start[n] = e;
}

// ---------------- bin edges: LDS multisplit with coalesced chunk flush ----------------
__global__ __launch_bounds__(256) void bin_edges(const int* __restrict__ src, const int* __restrict__ dst,
                                                 int* __restrict__ gcur, uint2* __restrict__ temp, int e) {
    __shared__ uint2 buf[MAXNB][CAP];
    __shared__ int cnt[MAXNB], c[MAXNB], sc[MAXNB], gb[MAXNB];
    __shared__ int pre[MAXNB + 1];

    int tid = threadIdx.x;
    if (tid < MAXNB) cnt[tid] = 0;
    __syncthreads();

    int i0 = blockIdx.x * 2048 + tid * 8;
    if (i0 + 8 <= e) {
        int4 s0 = *(const int4*)(src + i0);
        int4 s1 = *(const int4*)(src + i0 + 4);
        int4 d0 = *(const int4*)(dst + i0);
        int4 d1 = *(const int4*)(dst + i0 + 4);
        int ss[8] = {s0.x, s0.y, s0.z, s0.w, s1.x, s1.y, s1.z, s1.w};
        int dd[8] = {d0.x, d0.y, d0.z, d0.w, d1.x, d1.y, d1.z, d1.w};
#pragma unroll
        for (int k = 0; k < 8; ++k) {
            int b = dd[k] >> 10;
            uint2 pr = make_uint2((uint)ss[k], (uint)dd[k]);
            int p = atomicAdd(&cnt[b], 1);
            if (p < CAP) buf[b][p] = pr;
            else temp[atomicAdd(&gcur[b], 1)] = pr;
        }
    } else {
        for (int k = 0; k < 8; ++k) {
            if (i0 + k < e) {
                int b = dst[i0 + k] >> 10;
                uint2 pr = make_uint2((uint)src[i0 + k], (uint)dst[i0 + k]);
                int p = atomicAdd(&cnt[b], 1);
                if (p < CAP) buf[b][p] = pr;
                else temp[atomicAdd(&gcur[b], 1)] = pr;
            }
        }
    }
    __syncthreads();

    // prefix over stashed counts
    if (tid < MAXNB) {
        c[tid] = min(cnt[tid], CAP);
        sc[tid] = c[tid];
    }
    __syncthreads();
    for (int off = 1; off < MAXNB; off <<= 1) {
        int t = 0;
        if (tid < MAXNB && tid >= off) t = sc[tid - off];
        __syncthreads();
        if (tid < MAXNB) sc[tid] += t;
        __syncthreads();
    }
    if (tid < MAXNB) {
        pre[tid] = sc[tid] - c[tid];
        gb[tid] = (c[tid] > 0) ? atomicAdd(&gcur[tid], c[tid]) : 0;
    }
    if (tid == 0) pre[MAXNB] = sc[MAXNB - 1];
    __syncthreads();

    int S = pre[MAXNB];
    for (int idx = tid; idx < S; idx += 256) {
        int lo = 0, hi = MAXNB;
        while (hi - lo > 1) {
            int mid = (lo + hi) >> 1;
            if (pre[mid] <= idx) lo = mid;
            else hi = mid;
        }
        int ofs = idx - pre[lo];
        temp[gb[lo] + ofs] = buf[lo][ofs];
    }
}

// ---------------- build bucket: LDS deg/scan/place, writes L2-local ----------------
__global__ __launch_bounds__(1024) void build_bucket(const uint2* __restrict__ temp,
                                                     const int* __restrict__ bucket_base,
                                                     int* __restrict__ row_start, float* __restrict__ inv_deg,
                                                     int* __restrict__ csr_src, int n) {
    __shared__ int deg[1024], cur[1024], rs[1024];
    int tid = threadIdx.x;
    int b = blockIdx.x;
    int base = bucket_base[b];
    int ecnt = bucket_base[b + 1] - base;
    int node0 = b << 10;
    int ncnt = min(1024, n - node0);

    deg[tid] = 0;
    __syncthreads();
    for (int i = tid; i < ecnt; i += 1024) {
        int d = (int)temp[base + i].y - node0;
        atomicAdd(&deg[d], 1);
    }
    __syncthreads();
    // inclusive scan of deg -> rs
    rs[tid] = deg[tid];
    __syncthreads();
    for (int off = 1; off < 1024; off <<= 1) {
        int t = (tid >= off) ? rs[tid - off] : 0;
        __syncthreads();
        rs[tid] += t;
        __syncthreads();
    }
    int excl = rs[tid] - deg[tid];
    if (tid < ncnt) {
        int d = deg[tid];
        row_start[node0 + tid] = base + excl;
        inv_deg[node0 + tid] = d ? 1.0f / (float)d : 0.0f;
    }
    __syncthreads();
    rs[tid] = excl;  // repurpose as exclusive offsets
    cur[tid] = 0;
    __syncthreads();
    for (int i = tid; i < ecnt; i += 1024) {
        uint2 p = temp[base + i];
        int l = (int)p.y - node0;
        int pos = atomicAdd(&cur[l], 1);
        csr_src[base + rs[l] + pos] = (int)p.x;
    }
}

// ---------------- feature convert: f32 [n][128] -> bf16 cols 0..127 of [n][256] ----------------
__global__ __launch_bounds__(256) void convert_x(const float* __restrict__ x, ushort* __restrict__ xcat, int total8) {
    int i = blockIdx.x * 256 + threadIdx.x;
    if (i >= total8) return;
    int e = i * 8;
    int row = e >> 7, col = e & 127;
    float4 v0 = *(const float4*)(x + e);
    float4 v1 = *(const float4*)(x + e + 4);
    uint4 o;
    o.x = pack2(v0.x, v0.y);
    o.y = pack2(v0.z, v0.w);
    o.z = pack2(v1.x, v1.y);
    o.w = pack2(v1.z, v1.w);
    *(uint4*)(xcat + (size_t)row * 256 + col) = o;
}

// ---------------- weight convert ----------------
__global__ __launch_bounds__(256) void convert_w(const float* __restrict__ W1s, const float* __restrict__ W1n,
                                                 const float* __restrict__ W2s, const float* __restrict__ W2n,
                                                 ushort* __restrict__ w1cat, ushort* __restrict__ w2cat) {
    int idx = blockIdx.x * 256 + threadIdx.x;
    if (idx < 128 * 256) {
        int c = idx >> 8, k = idx & 255;
        float v = (k < 128) ? W1s[k * 128 + c] : W1n[(k - 128) * 128 + c];
        w1cat[idx] = f2bf(v);
    } else if (idx < 128 * 256 + 64 * 256) {
        int j = idx - 128 * 256;
        int c = j >> 8, k = j & 255;
        float v = (k < 128) ? W2s[k * 64 + c] : W2n[(k - 128) * 64 + c];
        w2cat[j] = f2bf(v);
    }
}

// ---------------- aggregation: wave per node, 4 edges/iter, bf16 rows of 256B ----------------
__global__ __launch_bounds__(256) void aggregate_bf16(const ushort* __restrict__ featbase,
                                                      const int* __restrict__ row_start,
                                                      const int* __restrict__ csr_src,
                                                      const float* __restrict__ inv_deg,
                                                      ushort* __restrict__ outbase, int n) {
    int wid = (blockIdx.x * 256 + threadIdx.x) >> 6;
    if (wid >= n) return;
    int lane = threadIdx.x & 63;
    int grp = lane >> 4, gl = lane & 15;

    int beg = row_start[wid];
    int end = row_start[wid + 1];

    float a[8];
#pragma unroll
    for (int j = 0; j < 8; ++j) a[j] = 0.f;

    for (int ei = beg + grp; ei < end; ei += 4) {
        int s = csr_src[ei];
        uint4 v = *(const uint4*)(featbase + (size_t)s * 256 + gl * 8);
        a[0] += __uint_as_float(v.x << 16);
        a[1] += __uint_as_float(v.x & 0xffff0000u);
        a[2] += __uint_as_float(v.y << 16);
        a[3] += __uint_as_float(v.y & 0xffff0000u);
        a[4] += __uint_as_float(v.z << 16);
        a[5] += __uint_as_float(v.z & 0xffff0000u);
        a[6] += __uint_as_float(v.w << 16);
        a[7] += __uint_as_float(v.w & 0xffff0000u);
    }
#pragma unroll
    for (int j = 0; j < 8; ++j) {
        a[j] += __shfl_xor(a[j], 16);
        a[j] += __shfl_xor(a[j], 32);
    }
    if (grp == 0) {
        float w = inv_deg[wid];
        uint4 o;
        o.x = pack2(a[0] * w, a[1] * w);
        o.y = pack2(a[2] * w, a[3] * w);
        o.z = pack2(a[4] * w, a[5] * w);
        o.w = pack2(a[6] * w, a[7] * w);
        *(uint4*)(outbase + (size_t)wid * 256 + gl * 8) = o;
    }
}

// ---------------- MFMA GEMM: Y[n][NCOL] = A[n][256] @ Wcat^T + bias ----------------
template <int NTILES, bool RELU, bool OUTBF16>
__global__ __launch_bounds__(256) void gemm_mfma(const ushort* __restrict__ A, const ushort* __restrict__ Wcat,
                                                 const float* __restrict__ bias, ushort* __restrict__ Yb,
                                                 float* __restrict__ Yf, int n) {
    constexpr int NCOL = NTILES * 16;
    __shared__ ushort Wlds[NCOL * 128];  // one 128-K chunk, XOR-swizzled rows of 256B

    int tid = threadIdx.x;
    int wave = tid >> 6, lane = tid & 63;
    int lrow = lane & 15, lk = lane >> 4;
    int m0 = blockIdx.x * 128 + wave * 32;

    int mA = min(m0 + lrow, n - 1);
    int mB = min(m0 + 16 + lrow, n - 1);
    const ushort* Arow0 = A + (size_t)mA * 256;
    const ushort* Arow1 = A + (size_t)mB * 256;

    f32x4 acc[2][NTILES];
#pragma unroll
    for (int mi = 0; mi < 2; ++mi)
#pragma unroll
        for (int nj = 0; nj < NTILES; ++nj) acc[mi][nj] = (f32x4)0.f;

    for (int chunk = 0; chunk < 2; ++chunk) {
        for (int f = tid; f < NCOL * 16; f += 256) {
            int c = f >> 4;
            int kk = (f & 15) * 8;
            uint4 w = *(const uint4*)(Wcat + c * 256 + chunk * 128 + kk);
            uint baddr = ((uint)(c * 256 + kk * 2)) ^ ((uint)(c & 7) << 4);
            *(uint4*)((char*)Wlds + baddr) = w;
        }
        __syncthreads();

#pragma unroll
        for (int ks = 0; ks < 4; ++ks) {
            int kbase = chunk * 128 + ks * 32 + lk * 8;
            bf16x8 a0 = *(const bf16x8*)(Arow0 + kbase);
            bf16x8 a1 = *(const bf16x8*)(Arow1 + kbase);
#pragma unroll
            for (int nj = 0; nj < NTILES; ++nj) {
                int c = nj * 16 + lrow;
                uint baddr = ((uint)(c * 256 + (ks * 32 + lk * 8) * 2)) ^ ((uint)(c & 7) << 4);
                bf16x8 b = *(const bf16x8*)((const char*)Wlds + baddr);
                acc[0][nj] = __builtin_amdgcn_mfma_f32_16x16x32_bf16(a0, b, acc[0][nj], 0, 0, 0);
                acc[1][nj] = __builtin_amdgcn_mfma_f32_16x16x32_bf16(a1, b, acc[1][nj], 0, 0, 0);
            }
        }
        __syncthreads();
    }

    // epilogue: C/D layout col=lane&15, row=(lane>>4)*4+r  [m89]
#pragma unroll
    for (int nj = 0; nj < NTILES; ++nj) {
        int col = nj * 16 + lrow;
        float bv = bias[col];
#pragma unroll
        for (int mi = 0; mi < 2; ++mi) {
#pragma unroll
            for (int r = 0; r < 4; ++r) {
                int row = m0 + mi * 16 + lk * 4 + r;
                if (row >= n) continue;
                float v = acc[mi][nj][r] + bv;
                if (RELU) v = fmaxf(v, 0.f);
                if (OUTBF16)
                    Yb[(size_t)row * 256 + col] = f2bf(v);
                else
                    Yf[(size_t)row * 64 + col] = v;
            }
        }
    }
}

extern "C" void kernel_launch(void* const* d_in, const int* in_sizes, int n_in,
                              void* d_out, int out_size, void* d_ws, size_t ws_size,
                              hipStream_t stream) {
    const float* x   = (const float*)d_in[0];
    const int*   src = (const int*)d_in[1];
    const int*   dst = (const int*)d_in[2];
    const float* W1s = (const float*)d_in[3];
    const float* W1n = (const float*)d_in[4];
    const float* b1  = (const float*)d_in[5];
    const float* W2s = (const float*)d_in[6];
    const float* W2n = (const float*)d_in[7];
    const float* b2  = (const float*)d_in[8];
    float* out = (float*)d_out;

    const int n = in_sizes[0] / D_FEAT;  // 100000
    const int e = in_sizes[1];           // 1600000
    const int nb = (n + 1023) >> 10;     // 98

    // ---- workspace carve ----
    char* ws = (char*)d_ws;
    auto take = [&](size_t bytes) {
        void* p = (void*)ws;
        ws += (bytes + 255) & ~(size_t)255;
        return p;
    };
    int*    bucket_cnt  = (int*)take((size_t)MAXNB * 4);
    int*    bucket_base = (int*)take((size_t)(MAXNB + 1) * 4);
    int*    gcur        = (int*)take((size_t)MAXNB * 4);
    int*    row_start   = (int*)take((size_t)(n + 1) * 4);
    float*  inv_deg     = (float*)take((size_t)n * 4);
    int*    csr_src     = (int*)take((size_t)e * 4);
    ushort* xcat        = (ushort*)take((size_t)n * 256 * 2);
    ushort* hcat        = (ushort*)take((size_t)n * 256 * 2);
    ushort* w1cat       = (ushort*)take((size_t)128 * 256 * 2);
    ushort* w2cat       = (ushort*)take((size_t)64 * 256 * 2);
    uint2*  temp        = (uint2*)hcat;  // alias: dead until gemm1 writes hcat

    hipMemsetAsync(bucket_cnt, 0, MAXNB * 4, stream);

    convert_w<<<(128 * 256 + 64 * 256 + 255) / 256, 256, 0, stream>>>(W1s, W1n, W2s, W2n, w1cat, w2cat);
    convert_x<<<(n * 16 + 255) / 256, 256, 0, stream>>>(x, xcat, n * 16);

    const int ebk = (e + 2047) / 2048;
    bucket_hist<<<ebk, 256, 0, stream>>>(dst, bucket_cnt, e, nb);
    bucket_scan<<<1, 128, 0, stream>>>(bucket_cnt, bucket_base, gcur, row_start, nb, n, e);
    bin_edges<<<ebk, 256, 0, stream>>>(src, dst, gcur, temp, e);
    build_bucket<<<nb, 1024, 0, stream>>>(temp, bucket_base, row_start, inv_deg, csr_src, n);

    // layer 1: agg(x) -> xcat[:,128:], then h = relu([x|agg] @ W1cat^T + b1) -> hcat[:,0:128]
    aggregate_bf16<<<(n + 3) / 4, 256, 0, stream>>>(xcat, row_start, csr_src, inv_deg, xcat + 128, n);
    gemm_mfma<8, true, true><<<(n + 127) / 128, 256, 0, stream>>>(xcat, w1cat, b1, hcat, nullptr, n);

    // layer 2: agg(h) -> hcat[:,128:], then out = [h|agg] @ W2cat^T + b2
    aggregate_bf16<<<(n + 3) / 4, 256, 0, stream>>>(hcat, row_start, csr_src, inv_deg, hcat + 128, n);
    gemm_mfma<4, false, false><<<(n + 127) / 128, 256, 0, stream>>>(hcat, w2cat, b2, nullptr, out, n);
}

// Round 4
// 357.547 us; speedup vs baseline: 2.1125x; 1.0395x over previous
//
#include <hip/hip_runtime.h>
#include <hip/hip_bf16.h>

// GraphSAGE 2-layer forward, bf16 datapath + cache-line-aware CSR build.
// agg: 16 lanes/node (one 256B row per group), 4 nodes/wave, unroll-2 edge
// prefetch for MLP. CSR: bucket_hist -> bucket_scan -> bin_edges (LDS multisplit)
// -> build_bucket (per-bucket LDS count/scan/place, L2-local writes).
// xcat/hcat: [n][256] bf16 rows = [feat(128) | agg(128)]; Wcat[N][256] bf16 B^T.

#define D_FEAT 128
#define MAXNB 128   // max buckets (n <= 131072), bucket = 1024 nodes
#define CAP 40      // LDS stash capacity per bucket per block-batch (mean ~21)

typedef __attribute__((ext_vector_type(8))) short bf16x8;
typedef __attribute__((ext_vector_type(4))) float f32x4;

__device__ __forceinline__ ushort f2bf(float f) {
    __hip_bfloat16 h = __float2bfloat16(f);
    return *(ushort*)&h;
}
__device__ __forceinline__ uint pack2(float lo, float hi) {
    return (uint)f2bf(lo) | ((uint)f2bf(hi) << 16);
}

// ---------------- bucket histogram: per-block LDS, one atomic/bucket/block ----------------
__global__ __launch_bounds__(256) void bucket_hist(const int* __restrict__ dst, int* __restrict__ bucket_cnt,
                                                   int e, int nb) {
    __shared__ int h[MAXNB];
    int tid = threadIdx.x;
    if (tid < MAXNB) h[tid] = 0;
    __syncthreads();
    int i0 = blockIdx.x * 2048 + tid * 8;
    if (i0 + 8 <= e) {
        int4 a = *(const int4*)(dst + i0);
        int4 b = *(const int4*)(dst + i0 + 4);
        atomicAdd(&h[a.x >> 10], 1);
        atomicAdd(&h[a.y >> 10], 1);
        atomicAdd(&h[a.z >> 10], 1);
        atomicAdd(&h[a.w >> 10], 1);
        atomicAdd(&h[b.x >> 10], 1);
        atomicAdd(&h[b.y >> 10], 1);
        atomicAdd(&h[b.z >> 10], 1);
        atomicAdd(&h[b.w >> 10], 1);
    } else {
        for (int k = 0; k < 8; ++k)
            if (i0 + k < e) atomicAdd(&h[dst[i0 + k] >> 10], 1);
    }
    __syncthreads();
    if (tid < nb && h[tid]) atomicAdd(&bucket_cnt[tid], h[tid]);
}

// ---------------- bucket scan ----------------
__global__ __launch_bounds__(128) void bucket_scan(const int* __restrict__ bucket_cnt, int* __restrict__ bucket_base,
                                                   int* __restrict__ gcur, int* __restrict__ row_start,
                                                   int nb, int n, int e) {
    __shared__ int sm[128];
    int tid = threadIdx.x;
    int v = (tid < nb) ? bucket_cnt[tid] : 0;
    sm[tid] = v;
    __syncthreads();
    for (int off = 1; off < 128; off <<= 1) {
        int t = (tid >= off) ? sm[tid - off] : 0;
        __syncthreads();
        sm[tid] += t;
        __syncthreads();
    }
    if (tid < nb) {
        int excl = sm[tid] - v;
        bucket_base[tid] = excl;
        gcur[tid] = excl;
    }
    if (tid == nb) bucket_base[tid] = e;  // nb < 128
    if (tid == 0) row_start[n] = e;
}

// ---------------- bin edges: LDS multisplit with coalesced chunk flush ----------------
__global__ __launch_bounds__(256) void bin_edges(const int* __restrict__ src, const int* __restrict__ dst,
                                                 int* __restrict__ gcur, uint2* __restrict__ temp, int e) {
    __shared__ uint2 buf[MAXNB][CAP];
    __shared__ int cnt[MAXNB], c[MAXNB], sc[MAXNB], gb[MAXNB];
    __shared__ int pre[MAXNB + 1];

    int tid = threadIdx.x;
    if (tid < MAXNB) cnt[tid] = 0;
    __syncthreads();

    int i0 = blockIdx.x * 2048 + tid * 8;
    if (i0 + 8 <= e) {
        int4 s0 = *(const int4*)(src + i0);
        int4 s1 = *(const int4*)(src + i0 + 4);
        int4 d0 = *(const int4*)(dst + i0);
        int4 d1 = *(const int4*)(dst + i0 + 4);
        int ss[8] = {s0.x, s0.y, s0.z, s0.w, s1.x, s1.y, s1.z, s1.w};
        int dd[8] = {d0.x, d0.y, d0.z, d0.w, d1.x, d1.y, d1.z, d1.w};
#pragma unroll
        for (int k = 0; k < 8; ++k) {
            int b = dd[k] >> 10;
            uint2 pr = make_uint2((uint)ss[k], (uint)dd[k]);
            int p = atomicAdd(&cnt[b], 1);
            if (p < CAP) buf[b][p] = pr;
            else temp[atomicAdd(&gcur[b], 1)] = pr;
        }
    } else {
        for (int k = 0; k < 8; ++k) {
            if (i0 + k < e) {
                int b = dst[i0 + k] >> 10;
                uint2 pr = make_uint2((uint)src[i0 + k], (uint)dst[i0 + k]);
                int p = atomicAdd(&cnt[b], 1);
                if (p < CAP) buf[b][p] = pr;
                else temp[atomicAdd(&gcur[b], 1)] = pr;
            }
        }
    }
    __syncthreads();

    if (tid < MAXNB) {
        c[tid] = min(cnt[tid], CAP);
        sc[tid] = c[tid];
    }
    __syncthreads();
    for (int off = 1; off < MAXNB; off <<= 1) {
        int t = 0;
        if (tid < MAXNB && tid >= off) t = sc[tid - off];
        __syncthreads();
        if (tid < MAXNB) sc[tid] += t;
        __syncthreads();
    }
    if (tid < MAXNB) {
        pre[tid] = sc[tid] - c[tid];
        gb[tid] = (c[tid] > 0) ? atomicAdd(&gcur[tid], c[tid]) : 0;
    }
    if (tid == 0) pre[MAXNB] = sc[MAXNB - 1];
    __syncthreads();

    int S = pre[MAXNB];
    for (int idx = tid; idx < S; idx += 256) {
        int lo = 0, hi = MAXNB;
        while (hi - lo > 1) {
            int mid = (lo + hi) >> 1;
            if (pre[mid] <= idx) lo = mid;
            else hi = mid;
        }
        int ofs = idx - pre[lo];
        temp[gb[lo] + ofs] = buf[lo][ofs];
    }
}

// ---------------- build bucket: LDS deg/scan/place, writes L2-local ----------------
__global__ __launch_bounds__(1024) void build_bucket(const uint2* __restrict__ temp,
                                                     const int* __restrict__ bucket_base,
                                                     int* __restrict__ row_start, float* __restrict__ inv_deg,
                                                     int* __restrict__ csr_src, int n) {
    __shared__ int deg[1024], cur[1024], rs[1024];
    int tid = threadIdx.x;
    int b = blockIdx.x;
    int base = bucket_base[b];
    int ecnt = bucket_base[b + 1] - base;
    int node0 = b << 10;
    int ncnt = min(1024, n - node0);

    deg[tid] = 0;
    __syncthreads();
    for (int i = tid; i < ecnt; i += 1024) {
        int d = (int)temp[base + i].y - node0;
        atomicAdd(&deg[d], 1);
    }
    __syncthreads();
    rs[tid] = deg[tid];
    __syncthreads();
    for (int off = 1; off < 1024; off <<= 1) {
        int t = (tid >= off) ? rs[tid - off] : 0;
        __syncthreads();
        rs[tid] += t;
        __syncthreads();
    }
    int excl = rs[tid] - deg[tid];
    if (tid < ncnt) {
        int d = deg[tid];
        row_start[node0 + tid] = base + excl;
        inv_deg[node0 + tid] = d ? 1.0f / (float)d : 0.0f;
    }
    __syncthreads();
    rs[tid] = excl;
    cur[tid] = 0;
    __syncthreads();
    for (int i = tid; i < ecnt; i += 1024) {
        uint2 p = temp[base + i];
        int l = (int)p.y - node0;
        int pos = atomicAdd(&cur[l], 1);
        csr_src[base + rs[l] + pos] = (int)p.x;
    }
}

// ---------------- fused convert: x -> xcat[:,0:128], weights -> w1cat/w2cat ----------------
__global__ __launch_bounds__(256) void convert_all(const float* __restrict__ x, ushort* __restrict__ xcat,
                                                   const float* __restrict__ W1s, const float* __restrict__ W1n,
                                                   const float* __restrict__ W2s, const float* __restrict__ W2n,
                                                   ushort* __restrict__ w1cat, ushort* __restrict__ w2cat,
                                                   int total8) {
    int i = blockIdx.x * 256 + threadIdx.x;
    if (i < total8) {
        int e = i * 8;
        int row = e >> 7, col = e & 127;
        float4 v0 = *(const float4*)(x + e);
        float4 v1 = *(const float4*)(x + e + 4);
        uint4 o;
        o.x = pack2(v0.x, v0.y);
        o.y = pack2(v0.z, v0.w);
        o.z = pack2(v1.x, v1.y);
        o.w = pack2(v1.z, v1.w);
        *(uint4*)(xcat + (size_t)row * 256 + col) = o;
    } else {
        int idx = i - total8;
        if (idx < 128 * 256) {
            int c = idx >> 8, k = idx & 255;
            float v = (k < 128) ? W1s[k * 128 + c] : W1n[(k - 128) * 128 + c];
            w1cat[idx] = f2bf(v);
        } else if (idx < 128 * 256 + 64 * 256) {
            int j = idx - 128 * 256;
            int c = j >> 8, k = j & 255;
            float v = (k < 128) ? W2s[k * 64 + c] : W2n[(k - 128) * 64 + c];
            w2cat[j] = f2bf(v);
        }
    }
}

// ---------------- aggregation: 16 lanes per node, 4 nodes/wave, unroll-2 ----------------
__global__ __launch_bounds__(256) void aggregate_bf16(const ushort* __restrict__ featbase,
                                                      const int* __restrict__ row_start,
                                                      const int* __restrict__ csr_src,
                                                      const float* __restrict__ inv_deg,
                                                      ushort* __restrict__ outbase, int n) {
    int node = (blockIdx.x * 256 + threadIdx.x) >> 4;
    if (node >= n) return;
    int gl = threadIdx.x & 15;

    int beg = row_start[node];
    int end = row_start[node + 1];

    float a[8];
#pragma unroll
    for (int j = 0; j < 8; ++j) a[j] = 0.f;

    const uint4* fb = (const uint4*)featbase;  // 32 uint4 per 512B row; feat half = first 16

    int ei = beg;
    for (; ei + 2 <= end; ei += 2) {
        int s0 = csr_src[ei];
        int s1 = csr_src[ei + 1];
        uint4 v0 = fb[(size_t)s0 * 32 + gl];
        uint4 v1 = fb[(size_t)s1 * 32 + gl];
        a[0] += __uint_as_float(v0.x << 16);
        a[1] += __uint_as_float(v0.x & 0xffff0000u);
        a[2] += __uint_as_float(v0.y << 16);
        a[3] += __uint_as_float(v0.y & 0xffff0000u);
        a[4] += __uint_as_float(v0.z << 16);
        a[5] += __uint_as_float(v0.z & 0xffff0000u);
        a[6] += __uint_as_float(v0.w << 16);
        a[7] += __uint_as_float(v0.w & 0xffff0000u);
        a[0] += __uint_as_float(v1.x << 16);
        a[1] += __uint_as_float(v1.x & 0xffff0000u);
        a[2] += __uint_as_float(v1.y << 16);
        a[3] += __uint_as_float(v1.y & 0xffff0000u);
        a[4] += __uint_as_float(v1.z << 16);
        a[5] += __uint_as_float(v1.z & 0xffff0000u);
        a[6] += __uint_as_float(v1.w << 16);
        a[7] += __uint_as_float(v1.w & 0xffff0000u);
    }
    if (ei < end) {
        int s = csr_src[ei];
        uint4 v = fb[(size_t)s * 32 + gl];
        a[0] += __uint_as_float(v.x << 16);
        a[1] += __uint_as_float(v.x & 0xffff0000u);
        a[2] += __uint_as_float(v.y << 16);
        a[3] += __uint_as_float(v.y & 0xffff0000u);
        a[4] += __uint_as_float(v.z << 16);
        a[5] += __uint_as_float(v.z & 0xffff0000u);
        a[6] += __uint_as_float(v.w << 16);
        a[7] += __uint_as_float(v.w & 0xffff0000u);
    }

    float w = inv_deg[node];
    uint4 o;
    o.x = pack2(a[0] * w, a[1] * w);
    o.y = pack2(a[2] * w, a[3] * w);
    o.z = pack2(a[4] * w, a[5] * w);
    o.w = pack2(a[6] * w, a[7] * w);
    *(uint4*)(outbase + (size_t)node * 256 + gl * 8) = o;
}

// ---------------- MFMA GEMM: Y[n][NCOL] = A[n][256] @ Wcat^T + bias ----------------
template <int NTILES, bool RELU, bool OUTBF16>
__global__ __launch_bounds__(256) void gemm_mfma(const ushort* __restrict__ A, const ushort* __restrict__ Wcat,
                                                 const float* __restrict__ bias, ushort* __restrict__ Yb,
                                                 float* __restrict__ Yf, int n) {
    constexpr int NCOL = NTILES * 16;
    __shared__ ushort Wlds[NCOL * 128];  // one 128-K chunk, XOR-swizzled rows of 256B

    int tid = threadIdx.x;
    int wave = tid >> 6, lane = tid & 63;
    int lrow = lane & 15, lk = lane >> 4;
    int m0 = blockIdx.x * 128 + wave * 32;

    int mA = min(m0 + lrow, n - 1);
    int mB = min(m0 + 16 + lrow, n - 1);
    const ushort* Arow0 = A + (size_t)mA * 256;
    const ushort* Arow1 = A + (size_t)mB * 256;

    f32x4 acc[2][NTILES];
#pragma unroll
    for (int mi = 0; mi < 2; ++mi)
#pragma unroll
        for (int nj = 0; nj < NTILES; ++nj) acc[mi][nj] = (f32x4)0.f;

    for (int chunk = 0; chunk < 2; ++chunk) {
        for (int f = tid; f < NCOL * 16; f += 256) {
            int c = f >> 4;
            int kk = (f & 15) * 8;
            uint4 w = *(const uint4*)(Wcat + c * 256 + chunk * 128 + kk);
            uint baddr = ((uint)(c * 256 + kk * 2)) ^ ((uint)(c & 7) << 4);
            *(uint4*)((char*)Wlds + baddr) = w;
        }
        __syncthreads();

#pragma unroll
        for (int ks = 0; ks < 4; ++ks) {
            int kbase = chunk * 128 + ks * 32 + lk * 8;
            bf16x8 a0 = *(const bf16x8*)(Arow0 + kbase);
            bf16x8 a1 = *(const bf16x8*)(Arow1 + kbase);
#pragma unroll
            for (int nj = 0; nj < NTILES; ++nj) {
                int c = nj * 16 + lrow;
                uint baddr = ((uint)(c * 256 + (ks * 32 + lk * 8) * 2)) ^ ((uint)(c & 7) << 4);
                bf16x8 b = *(const bf16x8*)((const char*)Wlds + baddr);
                acc[0][nj] = __builtin_amdgcn_mfma_f32_16x16x32_bf16(a0, b, acc[0][nj], 0, 0, 0);
                acc[1][nj] = __builtin_amdgcn_mfma_f32_16x16x32_bf16(a1, b, acc[1][nj], 0, 0, 0);
            }
        }
        __syncthreads();
    }

    // epilogue: C/D layout col=lane&15, row=(lane>>4)*4+r  [m89]
#pragma unroll
    for (int nj = 0; nj < NTILES; ++nj) {
        int col = nj * 16 + lrow;
        float bv = bias[col];
#pragma unroll
        for (int mi = 0; mi < 2; ++mi) {
#pragma unroll
            for (int r = 0; r < 4; ++r) {
                int row = m0 + mi * 16 + lk * 4 + r;
                if (row >= n) continue;
                float v = acc[mi][nj][r] + bv;
                if (RELU) v = fmaxf(v, 0.f);
                if (OUTBF16)
                    Yb[(size_t)row * 256 + col] = f2bf(v);
                else
                    Yf[(size_t)row * 64 + col] = v;
            }
        }
    }
}

extern "C" void kernel_launch(void* const* d_in, const int* in_sizes, int n_in,
                              void* d_out, int out_size, void* d_ws, size_t ws_size,
                              hipStream_t stream) {
    const float* x   = (const float*)d_in[0];
    const int*   src = (const int*)d_in[1];
    const int*   dst = (const int*)d_in[2];
    const float* W1s = (const float*)d_in[3];
    const float* W1n = (const float*)d_in[4];
    const float* b1  = (const float*)d_in[5];
    const float* W2s = (const float*)d_in[6];
    const float* W2n = (const float*)d_in[7];
    const float* b2  = (const float*)d_in[8];
    float* out = (float*)d_out;

    const int n = in_sizes[0] / D_FEAT;  // 100000
    const int e = in_sizes[1];           // 1600000
    const int nb = (n + 1023) >> 10;     // 98

    // ---- workspace carve ----
    char* ws = (char*)d_ws;
    auto take = [&](size_t bytes) {
        void* p = (void*)ws;
        ws += (bytes + 255) & ~(size_t)255;
        return p;
    };
    int*    bucket_cnt  = (int*)take((size_t)MAXNB * 4);
    int*    bucket_base = (int*)take((size_t)(MAXNB + 1) * 4);
    int*    gcur        = (int*)take((size_t)MAXNB * 4);
    int*    row_start   = (int*)take((size_t)(n + 1) * 4);
    float*  inv_deg     = (float*)take((size_t)n * 4);
    int*    csr_src     = (int*)take((size_t)e * 4);
    ushort* xcat        = (ushort*)take((size_t)n * 256 * 2);
    ushort* hcat        = (ushort*)take((size_t)n * 256 * 2);
    ushort* w1cat       = (ushort*)take((size_t)128 * 256 * 2);
    ushort* w2cat       = (ushort*)take((size_t)64 * 256 * 2);
    uint2*  temp        = (uint2*)hcat;  // alias: dead until gemm1 writes hcat

    hipMemsetAsync(bucket_cnt, 0, MAXNB * 4, stream);

    const int total8 = n * 16;
    const int cvt_items = total8 + 128 * 256 + 64 * 256;
    convert_all<<<(cvt_items + 255) / 256, 256, 0, stream>>>(x, xcat, W1s, W1n, W2s, W2n, w1cat, w2cat, total8);

    const int ebk = (e + 2047) / 2048;
    bucket_hist<<<ebk, 256, 0, stream>>>(dst, bucket_cnt, e, nb);
    bucket_scan<<<1, 128, 0, stream>>>(bucket_cnt, bucket_base, gcur, row_start, nb, n, e);
    bin_edges<<<ebk, 256, 0, stream>>>(src, dst, gcur, temp, e);
    build_bucket<<<nb, 1024, 0, stream>>>(temp, bucket_base, row_start, inv_deg, csr_src, n);

    // layer 1: agg(x) -> xcat[:,128:], then h = relu([x|agg] @ W1cat^T + b1) -> hcat[:,0:128]
    aggregate_bf16<<<(n * 16 + 255) / 256, 256, 0, stream>>>(xcat, row_start, csr_src, inv_deg, xcat + 128, n);
    gemm_mfma<8, true, true><<<(n + 127) / 128, 256, 0, stream>>>(xcat, w1cat, b1, hcat, nullptr, n);

    // layer 2: agg(h) -> hcat[:,128:], then out = [h|agg] @ W2cat^T + b2
    aggregate_bf16<<<(n * 16 + 255) / 256, 256, 0, stream>>>(hcat, row_start, csr_src, inv_deg, hcat + 128, n);
    gemm_mfma<4, false, false><<<(n + 127) / 128, 256, 0, stream>>>(hcat, w2cat, b2, nullptr, out, n);
}

// Round 5
// 355.042 us; speedup vs baseline: 2.1274x; 1.0071x over previous
//
#include <hip/hip_runtime.h>
#include <hip/hip_bf16.h>

// GraphSAGE 2-layer forward, bf16 datapath + cache-line-aware CSR build.
// agg: 16 lanes/node, grid-stride (2 nodes/group), unroll-4 gather MLP.
// CSR: bucket_hist -> bucket_scan -> bin_edges (LDS multisplit) -> build_bucket
// (wave-shfl scan). GEMM: mfma 16x16x32, A-fragments preloaded, W LDS-swizzled.
// xcat/hcat: [n_pad][256] bf16 rows = [feat(128) | agg(128)]; Wcat[N][256] bf16 B^T.

#define D_FEAT 128
#define MAXNB 128   // max buckets (n <= 131072), bucket = 1024 nodes
#define CAP 40      // LDS stash capacity per bucket per block-batch (mean ~21)

typedef __attribute__((ext_vector_type(8))) short bf16x8;
typedef __attribute__((ext_vector_type(4))) float f32x4;

__device__ __forceinline__ ushort f2bf(float f) {
    __hip_bfloat16 h = __float2bfloat16(f);
    return *(ushort*)&h;
}
__device__ __forceinline__ uint pack2(float lo, float hi) {
    return (uint)f2bf(lo) | ((uint)f2bf(hi) << 16);
}
__device__ __forceinline__ void acc8(float* a, uint4 v) {
    a[0] += __uint_as_float(v.x << 16);
    a[1] += __uint_as_float(v.x & 0xffff0000u);
    a[2] += __uint_as_float(v.y << 16);
    a[3] += __uint_as_float(v.y & 0xffff0000u);
    a[4] += __uint_as_float(v.z << 16);
    a[5] += __uint_as_float(v.z & 0xffff0000u);
    a[6] += __uint_as_float(v.w << 16);
    a[7] += __uint_as_float(v.w & 0xffff0000u);
}

// ---------------- bucket histogram ----------------
__global__ __launch_bounds__(256) void bucket_hist(const int* __restrict__ dst, int* __restrict__ bucket_cnt,
                                                   int e, int nb) {
    __shared__ int h[MAXNB];
    int tid = threadIdx.x;
    if (tid < MAXNB) h[tid] = 0;
    __syncthreads();
    int i0 = blockIdx.x * 2048 + tid * 8;
    if (i0 + 8 <= e) {
        int4 a = *(const int4*)(dst + i0);
        int4 b = *(const int4*)(dst + i0 + 4);
        atomicAdd(&h[a.x >> 10], 1);
        atomicAdd(&h[a.y >> 10], 1);
        atomicAdd(&h[a.z >> 10], 1);
        atomicAdd(&h[a.w >> 10], 1);
        atomicAdd(&h[b.x >> 10], 1);
        atomicAdd(&h[b.y >> 10], 1);
        atomicAdd(&h[b.z >> 10], 1);
        atomicAdd(&h[b.w >> 10], 1);
    } else {
        for (int k = 0; k < 8; ++k)
            if (i0 + k < e) atomicAdd(&h[dst[i0 + k] >> 10], 1);
    }
    __syncthreads();
    if (tid < nb && h[tid]) atomicAdd(&bucket_cnt[tid], h[tid]);
}

// ---------------- bucket scan ----------------
__global__ __launch_bounds__(128) void bucket_scan(const int* __restrict__ bucket_cnt, int* __restrict__ bucket_base,
                                                   int* __restrict__ gcur, int* __restrict__ row_start,
                                                   int nb, int n, int e) {
    __shared__ int sm[128];
    int tid = threadIdx.x;
    int v = (tid < nb) ? bucket_cnt[tid] : 0;
    sm[tid] = v;
    __syncthreads();
    for (int off = 1; off < 128; off <<= 1) {
        int t = (tid >= off) ? sm[tid - off] : 0;
        __syncthreads();
        sm[tid] += t;
        __syncthreads();
    }
    if (tid < nb) {
        int excl = sm[tid] - v;
        bucket_base[tid] = excl;
        gcur[tid] = excl;
    }
    if (tid == nb) bucket_base[tid] = e;  // nb < 128
    if (tid == 0) row_start[n] = e;
}

// ---------------- bin edges: LDS multisplit ----------------
__global__ __launch_bounds__(256) void bin_edges(const int* __restrict__ src, const int* __restrict__ dst,
                                                 int* __restrict__ gcur, uint2* __restrict__ temp, int e) {
    __shared__ uint2 buf[MAXNB][CAP];
    __shared__ int cnt[MAXNB], c[MAXNB], sc[MAXNB], gb[MAXNB];
    __shared__ int pre[MAXNB + 1];

    int tid = threadIdx.x;
    if (tid < MAXNB) cnt[tid] = 0;
    __syncthreads();

    int i0 = blockIdx.x * 2048 + tid * 8;
    if (i0 + 8 <= e) {
        int4 s0 = *(const int4*)(src + i0);
        int4 s1 = *(const int4*)(src + i0 + 4);
        int4 d0 = *(const int4*)(dst + i0);
        int4 d1 = *(const int4*)(dst + i0 + 4);
        int ss[8] = {s0.x, s0.y, s0.z, s0.w, s1.x, s1.y, s1.z, s1.w};
        int dd[8] = {d0.x, d0.y, d0.z, d0.w, d1.x, d1.y, d1.z, d1.w};
#pragma unroll
        for (int k = 0; k < 8; ++k) {
            int b = dd[k] >> 10;
            uint2 pr = make_uint2((uint)ss[k], (uint)dd[k]);
            int p = atomicAdd(&cnt[b], 1);
            if (p < CAP) buf[b][p] = pr;
            else temp[atomicAdd(&gcur[b], 1)] = pr;
        }
    } else {
        for (int k = 0; k < 8; ++k) {
            if (i0 + k < e) {
                int b = dst[i0 + k] >> 10;
                uint2 pr = make_uint2((uint)src[i0 + k], (uint)dst[i0 + k]);
                int p = atomicAdd(&cnt[b], 1);
                if (p < CAP) buf[b][p] = pr;
                else temp[atomicAdd(&gcur[b], 1)] = pr;
            }
        }
    }
    __syncthreads();

    if (tid < MAXNB) {
        c[tid] = min(cnt[tid], CAP);
        sc[tid] = c[tid];
    }
    __syncthreads();
    for (int off = 1; off < MAXNB; off <<= 1) {
        int t = 0;
        if (tid < MAXNB && tid >= off) t = sc[tid - off];
        __syncthreads();
        if (tid < MAXNB) sc[tid] += t;
        __syncthreads();
    }
    if (tid < MAXNB) {
        pre[tid] = sc[tid] - c[tid];
        gb[tid] = (c[tid] > 0) ? atomicAdd(&gcur[tid], c[tid]) : 0;
    }
    if (tid == 0) pre[MAXNB] = sc[MAXNB - 1];
    __syncthreads();

    int S = pre[MAXNB];
    for (int idx = tid; idx < S; idx += 256) {
        int lo = 0, hi = MAXNB;
        while (hi - lo > 1) {
            int mid = (lo + hi) >> 1;
            if (pre[mid] <= idx) lo = mid;
            else hi = mid;
        }
        int ofs = idx - pre[lo];
        temp[gb[lo] + ofs] = buf[lo][ofs];
    }
}

// ---------------- build bucket: wave-shfl scan, L2-local writes ----------------
__global__ __launch_bounds__(1024) void build_bucket(const uint2* __restrict__ temp,
                                                     const int* __restrict__ bucket_base,
                                                     int* __restrict__ row_start, float* __restrict__ inv_deg,
                                                     int* __restrict__ csr_src, int n) {
    __shared__ int deg[1024], cur[1024], rs[1024], wsum[16];
    int tid = threadIdx.x;
    int b = blockIdx.x;
    int base = bucket_base[b];
    int ecnt = bucket_base[b + 1] - base;
    int node0 = b << 10;
    int ncnt = min(1024, n - node0);

    deg[tid] = 0;
    __syncthreads();
    for (int i = tid; i < ecnt; i += 1024) {
        int d = (int)temp[base + i].y - node0;
        atomicAdd(&deg[d], 1);
    }
    __syncthreads();

    // inclusive scan via wave shfl + cross-wave combine
    int d = deg[tid];
    int v = d;
#pragma unroll
    for (int off = 1; off < 64; off <<= 1) {
        int t = __shfl_up(v, off);
        if ((tid & 63) >= off) v += t;
    }
    int wv = tid >> 6;
    if ((tid & 63) == 63) wsum[wv] = v;
    __syncthreads();
    if (tid < 16) {
        int w = wsum[tid];
#pragma unroll
        for (int off = 1; off < 16; off <<= 1) {
            int t = __shfl_up(w, off);
            if (tid >= off) w += t;
        }
        wsum[tid] = w;
    }
    __syncthreads();
    int incl = v + (wv ? wsum[wv - 1] : 0);
    int excl = incl - d;

    if (tid < ncnt) {
        row_start[node0 + tid] = base + excl;
        inv_deg[node0 + tid] = d ? 1.0f / (float)d : 0.0f;
    }
    rs[tid] = excl;
    cur[tid] = 0;
    __syncthreads();
    for (int i = tid; i < ecnt; i += 1024) {
        uint2 p = temp[base + i];
        int l = (int)p.y - node0;
        int pos = atomicAdd(&cur[l], 1);
        csr_src[base + rs[l] + pos] = (int)p.x;
    }
}

// ---------------- fused convert: x -> xcat[:,0:128], weights -> w1cat/w2cat ----------------
__global__ __launch_bounds__(256) void convert_all(const float* __restrict__ x, ushort* __restrict__ xcat,
                                                   const float* __restrict__ W1s, const float* __restrict__ W1n,
                                                   const float* __restrict__ W2s, const float* __restrict__ W2n,
                                                   ushort* __restrict__ w1cat, ushort* __restrict__ w2cat,
                                                   int total8) {
    int i = blockIdx.x * 256 + threadIdx.x;
    if (i < total8) {
        int e = i * 8;
        int row = e >> 7, col = e & 127;
        float4 v0 = *(const float4*)(x + e);
        float4 v1 = *(const float4*)(x + e + 4);
        uint4 o;
        o.x = pack2(v0.x, v0.y);
        o.y = pack2(v0.z, v0.w);
        o.z = pack2(v1.x, v1.y);
        o.w = pack2(v1.z, v1.w);
        *(uint4*)(xcat + (size_t)row * 256 + col) = o;
    } else {
        int idx = i - total8;
        if (idx < 128 * 256) {
            int c = idx >> 8, k = idx & 255;
            float v = (k < 128) ? W1s[k * 128 + c] : W1n[(k - 128) * 128 + c];
            w1cat[idx] = f2bf(v);
        } else if (idx < 128 * 256 + 64 * 256) {
            int j = idx - 128 * 256;
            int c = j >> 8, k = j & 255;
            float v = (k < 128) ? W2s[k * 64 + c] : W2n[(k - 128) * 64 + c];
            w2cat[j] = f2bf(v);
        }
    }
}

// ---------------- aggregation: 16 lanes/node, grid-stride, unroll-4 ----------------
__global__ __launch_bounds__(256) void aggregate_bf16(const ushort* __restrict__ featbase,
                                                      const int* __restrict__ row_start,
                                                      const int* __restrict__ csr_src,
                                                      const float* __restrict__ inv_deg,
                                                      ushort* __restrict__ outbase, int n) {
    int g = (blockIdx.x * 256 + threadIdx.x) >> 4;
    int ngroups = gridDim.x * 16;
    int gl = threadIdx.x & 15;
    const uint4* fb = (const uint4*)featbase;  // 32 uint4 per 512B row

    for (int node = g; node < n; node += ngroups) {
        int beg = row_start[node];
        int end = row_start[node + 1];

        float a[8];
#pragma unroll
        for (int j = 0; j < 8; ++j) a[j] = 0.f;

        int ei = beg;
        for (; ei + 4 <= end; ei += 4) {
            int s0 = csr_src[ei];
            int s1 = csr_src[ei + 1];
            int s2 = csr_src[ei + 2];
            int s3 = csr_src[ei + 3];
            uint4 v0 = fb[(size_t)s0 * 32 + gl];
            uint4 v1 = fb[(size_t)s1 * 32 + gl];
            uint4 v2 = fb[(size_t)s2 * 32 + gl];
            uint4 v3 = fb[(size_t)s3 * 32 + gl];
            acc8(a, v0);
            acc8(a, v1);
            acc8(a, v2);
            acc8(a, v3);
        }
        for (; ei < end; ++ei) {
            int s = csr_src[ei];
            uint4 v = fb[(size_t)s * 32 + gl];
            acc8(a, v);
        }

        float w = inv_deg[node];
        uint4 o;
        o.x = pack2(a[0] * w, a[1] * w);
        o.y = pack2(a[2] * w, a[3] * w);
        o.z = pack2(a[4] * w, a[5] * w);
        o.w = pack2(a[6] * w, a[7] * w);
        *(uint4*)(outbase + (size_t)node * 256 + gl * 8) = o;
    }
}

// ---------------- MFMA GEMM: Y[n][NCOL] = A[n_pad][256] @ Wcat^T + bias ----------------
template <int NTILES, bool RELU, bool OUTBF16>
__global__ __launch_bounds__(256) void gemm_mfma(const ushort* __restrict__ A, const ushort* __restrict__ Wcat,
                                                 const float* __restrict__ bias, ushort* __restrict__ Yb,
                                                 float* __restrict__ Yf, int n) {
    constexpr int NCOL = NTILES * 16;
    __shared__ ushort Wlds[NCOL * 128];  // one 128-K chunk, XOR-swizzled rows of 256B

    int tid = threadIdx.x;
    int wave = tid >> 6, lane = tid & 63;
    int lrow = lane & 15, lk = lane >> 4;
    int m0 = blockIdx.x * 128 + wave * 32;

    // preload all A fragments (rows padded to 128-multiple; pad bytes harmless)
    const ushort* Arow0 = A + (size_t)(m0 + lrow) * 256;
    const ushort* Arow1 = Arow0 + 16 * 256;
    bf16x8 af0[8], af1[8];  // [chunk*4+ks]
#pragma unroll
    for (int c = 0; c < 2; ++c)
#pragma unroll
        for (int ks = 0; ks < 4; ++ks) {
            int kb = c * 128 + ks * 32 + lk * 8;
            af0[c * 4 + ks] = *(const bf16x8*)(Arow0 + kb);
            af1[c * 4 + ks] = *(const bf16x8*)(Arow1 + kb);
        }

    f32x4 acc[2][NTILES];
#pragma unroll
    for (int mi = 0; mi < 2; ++mi)
#pragma unroll
        for (int nj = 0; nj < NTILES; ++nj) acc[mi][nj] = (f32x4)0.f;

    for (int chunk = 0; chunk < 2; ++chunk) {
        for (int f = tid; f < NCOL * 16; f += 256) {
            int c = f >> 4;
            int kk = (f & 15) * 8;
            uint4 w = *(const uint4*)(Wcat + c * 256 + chunk * 128 + kk);
            uint baddr = ((uint)(c * 256 + kk * 2)) ^ ((uint)(c & 7) << 4);
            *(uint4*)((char*)Wlds + baddr) = w;
        }
        __syncthreads();

#pragma unroll
        for (int ks = 0; ks < 4; ++ks) {
#pragma unroll
            for (int nj = 0; nj < NTILES; ++nj) {
                int c = nj * 16 + lrow;
                uint baddr = ((uint)(c * 256 + (ks * 32 + lk * 8) * 2)) ^ ((uint)(c & 7) << 4);
                bf16x8 b = *(const bf16x8*)((const char*)Wlds + baddr);
                acc[0][nj] = __builtin_amdgcn_mfma_f32_16x16x32_bf16(af0[chunk * 4 + ks], b, acc[0][nj], 0, 0, 0);
                acc[1][nj] = __builtin_amdgcn_mfma_f32_16x16x32_bf16(af1[chunk * 4 + ks], b, acc[1][nj], 0, 0, 0);
            }
        }
        __syncthreads();
    }

    // epilogue: C/D layout col=lane&15, row=(lane>>4)*4+r  [m89]
#pragma unroll
    for (int nj = 0; nj < NTILES; ++nj) {
        int col = nj * 16 + lrow;
        float bv = bias[col];
#pragma unroll
        for (int mi = 0; mi < 2; ++mi) {
#pragma unroll
            for (int r = 0; r < 4; ++r) {
                int row = m0 + mi * 16 + lk * 4 + r;
                if (row >= n) continue;
                float v = acc[mi][nj][r] + bv;
                if (RELU) v = fmaxf(v, 0.f);
                if (OUTBF16)
                    Yb[(size_t)row * 256 + col] = f2bf(v);
                else
                    Yf[(size_t)row * 64 + col] = v;
            }
        }
    }
}

extern "C" void kernel_launch(void* const* d_in, const int* in_sizes, int n_in,
                              void* d_out, int out_size, void* d_ws, size_t ws_size,
                              hipStream_t stream) {
    const float* x   = (const float*)d_in[0];
    const int*   src = (const int*)d_in[1];
    const int*   dst = (const int*)d_in[2];
    const float* W1s = (const float*)d_in[3];
    const float* W1n = (const float*)d_in[4];
    const float* b1  = (const float*)d_in[5];
    const float* W2s = (const float*)d_in[6];
    const float* W2n = (const float*)d_in[7];
    const float* b2  = (const float*)d_in[8];
    float* out = (float*)d_out;

    const int n = in_sizes[0] / D_FEAT;       // 100000
    const int e = in_sizes[1];                // 1600000
    const int nb = (n + 1023) >> 10;          // 98
    const int n_pad = (n + 127) & ~127;       // 128-row multiple for GEMM

    // ---- workspace carve ----
    char* ws = (char*)d_ws;
    auto take = [&](size_t bytes) {
        void* p = (void*)ws;
        ws += (bytes + 255) & ~(size_t)255;
        return p;
    };
    int*    bucket_cnt  = (int*)take((size_t)MAXNB * 4);
    int*    bucket_base = (int*)take((size_t)(MAXNB + 1) * 4);
    int*    gcur        = (int*)take((size_t)MAXNB * 4);
    int*    row_start   = (int*)take((size_t)(n + 1) * 4);
    float*  inv_deg     = (float*)take((size_t)n * 4);
    int*    csr_src     = (int*)take((size_t)e * 4);
    ushort* xcat        = (ushort*)take((size_t)n_pad * 256 * 2);
    ushort* hcat        = (ushort*)take((size_t)n_pad * 256 * 2);
    ushort* w1cat       = (ushort*)take((size_t)128 * 256 * 2);
    ushort* w2cat       = (ushort*)take((size_t)64 * 256 * 2);
    uint2*  temp        = (uint2*)hcat;  // alias: dead until gemm1 writes hcat

    hipMemsetAsync(bucket_cnt, 0, MAXNB * 4, stream);

    const int total8 = n * 16;
    const int cvt_items = total8 + 128 * 256 + 64 * 256;
    convert_all<<<(cvt_items + 255) / 256, 256, 0, stream>>>(x, xcat, W1s, W1n, W2s, W2n, w1cat, w2cat, total8);

    const int ebk = (e + 2047) / 2048;
    bucket_hist<<<ebk, 256, 0, stream>>>(dst, bucket_cnt, e, nb);
    bucket_scan<<<1, 128, 0, stream>>>(bucket_cnt, bucket_base, gcur, row_start, nb, n, e);
    bin_edges<<<ebk, 256, 0, stream>>>(src, dst, gcur, temp, e);
    build_bucket<<<nb, 1024, 0, stream>>>(temp, bucket_base, row_start, inv_deg, csr_src, n);

    const int agg_blocks = 3125;  // 50000 groups -> exactly 2 nodes/group

    // layer 1: agg(x) -> xcat[:,128:], then h = relu([x|agg] @ W1cat^T + b1) -> hcat[:,0:128]
    aggregate_bf16<<<agg_blocks, 256, 0, stream>>>(xcat, row_start, csr_src, inv_deg, xcat + 128, n);
    gemm_mfma<8, true, true><<<n_pad / 128, 256, 0, stream>>>(xcat, w1cat, b1, hcat, nullptr, n);

    // layer 2: agg(h) -> hcat[:,128:], then out = [h|agg] @ W2cat^T + b2
    aggregate_bf16<<<agg_blocks, 256, 0, stream>>>(hcat, row_start, csr_src, inv_deg, hcat + 128, n);
    gemm_mfma<4, false, false><<<n_pad / 128, 256, 0, stream>>>(hcat, w2cat, b2, nullptr, out, n);
}